// Round 3
// baseline (516.139 us; speedup 1.0000x reference)
//
#include <hip/hip_runtime.h>
#include <hip/hip_bf16.h>

#define C_DIM 128
#define EPS_LN 1e-5f

typedef short bf16x8 __attribute__((ext_vector_type(8)));
typedef float f32x4  __attribute__((ext_vector_type(4)));
typedef __hip_bfloat16 bf16;

__device__ inline unsigned short f2bu(float f) {
    bf16 h = __float2bfloat16(f);
    return *reinterpret_cast<unsigned short*>(&h);
}
__device__ inline float blo(unsigned int u) { return __uint_as_float(u << 16); }
__device__ inline float bhi(unsigned int u) { return __uint_as_float(u & 0xffff0000u); }
__device__ inline ushort4 pack4(float a, float b, float c, float d) {
    ushort4 r; r.x = f2bu(a); r.y = f2bu(b); r.z = f2bu(c); r.w = f2bu(d); return r;
}

// async global->LDS DMA, 16B per lane. LDS dest is WAVE-UNIFORM base;
// HW writes lane l's 16B at base + l*16. Global src is per-lane.
__device__ inline void async_copy16(const bf16* g, bf16* s) {
    __builtin_amdgcn_global_load_lds(
        (const __attribute__((address_space(1))) unsigned int*)g,
        (__attribute__((address_space(3))) unsigned int*)s,
        16, 0, 0);
}

// ---------------- weights convert+transpose + bias pack, ONE dispatch ------
// dst (bf16): Wqt|Wkt|Wvt|Wot (4x 128*128) | Wt1[512][128] | Wt2[128][512]
// then packed fp32 bqkv[384] right after.
__global__ __launch_bounds__(256) void wconv_all(
    const float* __restrict__ Wq, const float* __restrict__ Wk,
    const float* __restrict__ Wv, const float* __restrict__ Wo,
    const float* __restrict__ W1, const float* __restrict__ W2,
    const float* __restrict__ bq, const float* __restrict__ bk,
    const float* __restrict__ bv, bf16* __restrict__ dst) {
    int idx = blockIdx.x * 256 + threadIdx.x;
    if (idx < 65536) {                       // four 128x128 weights
        int r = idx >> 14, o = idx & 16383;
        int k = o >> 7, nn = o & 127;
        const float* W = (r == 0) ? Wq : (r == 1) ? Wk : (r == 2) ? Wv : Wo;
        dst[(r << 14) + nn * 128 + k] = __float2bfloat16(W[o]);
    } else if (idx < 131072) {               // W1 [128,512] -> Wt1[n][k]
        int o = idx - 65536;
        int k = o >> 9, nn = o & 511;
        dst[65536 + nn * 128 + k] = __float2bfloat16(W1[o]);
    } else if (idx < 196608) {               // W2 [512,128] -> Wt2[n][k]
        int o = idx - 131072;
        int k = o >> 7, nn = o & 127;
        dst[131072 + nn * 512 + k] = __float2bfloat16(W2[o]);
    } else if (idx < 196992) {               // packed bqkv[384] fp32
        int j = idx - 196608;
        int grp = j >> 7, col = j & 127;
        const float* bp = (grp == 0) ? bq : (grp == 1) ? bk : bv;
        ((float*)(dst + 196608))[j] = bp[col];
    }
}

__global__ __launch_bounds__(256) void zeroi_kernel(int* __restrict__ p, int n) {
    int i = blockIdx.x * 256 + threadIdx.x;
    if (i < n) p[i] = 0;
}

// ---------------- LayerNorm fp32 -> bf16, one wave per row -----------------
__global__ __launch_bounds__(256) void ln_kernel(
    const float* __restrict__ x, const float* __restrict__ g,
    const float* __restrict__ b, bf16* __restrict__ out, int n) {
    int wave = threadIdx.x >> 6;
    int lane = threadIdx.x & 63;
    int row = blockIdx.x * 4 + wave;
    if (row >= n) return;
    float2 v = ((const float2*)(x + (size_t)row * C_DIM))[lane];
    float s  = v.x + v.y;
    float ss = v.x * v.x + v.y * v.y;
    #pragma unroll
    for (int o = 1; o < 64; o <<= 1) {
        s  += __shfl_xor(s, o);
        ss += __shfl_xor(ss, o);
    }
    float mu  = s * (1.0f / C_DIM);
    float var = ss * (1.0f / C_DIM) - mu * mu;
    float rs  = rsqrtf(var + EPS_LN);
    float2 gg = ((const float2*)g)[lane];
    float2 bb = ((const float2*)b)[lane];
    __hip_bfloat162 o2;
    o2.x = __float2bfloat16((v.x - mu) * rs * gg.x + bb.x);
    o2.y = __float2bfloat16((v.y - mu) * rs * gg.y + bb.y);
    ((__hip_bfloat162*)(out + (size_t)row * C_DIM))[lane] = o2;
}

// ---------------- MFMA GEMM: B LDS-staged (DMA+swizzle), A direct-to-reg ---
// Block: 128 rows x 128 cols of C; 4 waves, each 32 rows x 128 cols.
// A [M,lda] bf16 row-major; Bt [Ncols][Kfull] bf16 (row = output col).
// A has ZERO intra-block LDS reuse (each frag element read once) -> load
// straight to VGPRs, coalesced 16B/lane, issued concurrent with B DMA.
// B has 4x reuse (every wave reads the whole tile) -> LDS via async DMA,
// XOR-swizzled source + swizzled read (rule: both-sides-or-neither).
// LDS = 32KB -> 4 blocks/CU (launch_bounds caps VGPR at 128).
// Tail: clamp source row to M-1 (results masked in epilogue).
// Operand-swapped mfma(bf, af, acc): lane(m,q) reg r = C[row0+..+m][ct*16+q*4+r].
template<bool OUTBF16, bool RELU, bool FUSE_LN, int KSTEPS>
__global__ __launch_bounds__(256, 4) void gemm_lds(
    const bf16* __restrict__ A, int lda,
    const bf16* __restrict__ Bt, int Kfull,
    const float* __restrict__ biasBase,
    void* __restrict__ Cd, int ldc, size_t obStride,
    const float* __restrict__ resid, int ldres,
    int M,
    const float* __restrict__ g, const float* __restrict__ be,
    bf16* __restrict__ h2) {
    __shared__ bf16 Bs[128][128];
    int tid  = threadIdx.x;
    int lane = tid & 63;
    int w    = tid >> 6;
    int m = lane & 15, q = lane >> 4;
    int row0 = blockIdx.x * 128;
    const bf16* Bbase = Bt + (size_t)blockIdx.y * 128 * Kfull;

    f32x4 acc[2][8];
    #pragma unroll
    for (int rt = 0; rt < 2; rt++)
        #pragma unroll
        for (int ct = 0; ct < 8; ct++) acc[rt][ct] = (f32x4){0.f, 0.f, 0.f, 0.f};

    int rsub  = lane >> 4;      // 0..3: this lane's dest row within a 4-row DMA call
    int cslot = lane & 15;      // this lane's 16B slot within the row

    int ar0 = row0 + w * 32 + m;      if (ar0 > M - 1) ar0 = M - 1;
    int ar1 = row0 + w * 32 + 16 + m; if (ar1 > M - 1) ar1 = M - 1;
    const bf16* arow0 = A + (size_t)ar0 * lda + q * 8;
    const bf16* arow1 = A + (size_t)ar1 * lda + q * 8;

    for (int kt = 0; kt < KSTEPS; kt++) {
        // stage B tile [128][128] via 8 async DMA calls per wave
        #pragma unroll
        for (int i = 0; i < 8; i++) {
            int brow = w * 32 + i * 4 + rsub;                 // dest row 0..127
            int scol = (cslot ^ (brow & 7)) << 3;             // swizzled src slot (elems)
            async_copy16(Bbase + (size_t)brow * Kfull + kt * 128 + scol, &Bs[w * 32 + i * 4][0]);
        }
        // A fragments: direct global -> VGPR (overlaps the B DMA)
        bf16x8 af0[4], af1[4];
        #pragma unroll
        for (int ks = 0; ks < 4; ks++) {
            af0[ks] = *(const bf16x8*)(arow0 + kt * 128 + ks * 32);
            af1[ks] = *(const bf16x8*)(arow1 + kt * 128 + ks * 32);
        }
        __syncthreads();
        #pragma unroll
        for (int ks = 0; ks < 4; ks++) {
            int sofs = ((ks * 4 + q) ^ (m & 7)) << 3;         // swizzled read offset
            #pragma unroll
            for (int ct = 0; ct < 8; ct++) {
                bf16x8 bf = *(const bf16x8*)&Bs[ct * 16 + m][sofs];
                acc[0][ct] = __builtin_amdgcn_mfma_f32_16x16x32_bf16(bf, af0[ks], acc[0][ct], 0, 0, 0);
                acc[1][ct] = __builtin_amdgcn_mfma_f32_16x16x32_bf16(bf, af1[ks], acc[1][ct], 0, 0, 0);
            }
        }
        if (kt + 1 < KSTEPS) __syncthreads();
    }

    // ---- epilogue ----
    #pragma unroll
    for (int rt = 0; rt < 2; rt++) {
        int row = row0 + w * 32 + rt * 16 + m;
        bool valid = row < M;
        float vals[8][4];
        #pragma unroll
        for (int ct = 0; ct < 8; ct++) {
            int col = ct * 16 + q * 4;
            float4 bv = make_float4(0.f, 0.f, 0.f, 0.f);
            if (biasBase) bv = *(const float4*)(biasBase + blockIdx.y * 128 + col);
            float4 rv = make_float4(0.f, 0.f, 0.f, 0.f);
            if (resid && valid) rv = *(const float4*)(resid + (size_t)row * ldres + col);
            vals[ct][0] = acc[rt][ct][0] + bv.x + rv.x;
            vals[ct][1] = acc[rt][ct][1] + bv.y + rv.y;
            vals[ct][2] = acc[rt][ct][2] + bv.z + rv.z;
            vals[ct][3] = acc[rt][ct][3] + bv.w + rv.w;
        }
        if (FUSE_LN) {
            // row spans lanes {m, m+16, m+32, m+48}: reduce over q via xor 16,32
            float s1 = 0.f, s2 = 0.f;
            #pragma unroll
            for (int ct = 0; ct < 8; ct++)
                #pragma unroll
                for (int r = 0; r < 4; r++) { s1 += vals[ct][r]; s2 += vals[ct][r] * vals[ct][r]; }
            s1 += __shfl_xor(s1, 16); s1 += __shfl_xor(s1, 32);
            s2 += __shfl_xor(s2, 16); s2 += __shfl_xor(s2, 32);
            float mu  = s1 * (1.0f / 128.f);
            float var = s2 * (1.0f / 128.f) - mu * mu;
            float rs  = rsqrtf(var + EPS_LN);
            if (valid) {
                #pragma unroll
                for (int ct = 0; ct < 8; ct++) {
                    int col = ct * 16 + q * 4;
                    *(float4*)((float*)Cd + (size_t)row * ldc + col) =
                        make_float4(vals[ct][0], vals[ct][1], vals[ct][2], vals[ct][3]);
                    float4 gg = *(const float4*)(g + col);
                    float4 bb = *(const float4*)(be + col);
                    *(ushort4*)(h2 + (size_t)row * 128 + col) =
                        pack4((vals[ct][0] - mu) * rs * gg.x + bb.x,
                              (vals[ct][1] - mu) * rs * gg.y + bb.y,
                              (vals[ct][2] - mu) * rs * gg.z + bb.z,
                              (vals[ct][3] - mu) * rs * gg.w + bb.w);
                }
            }
        } else if (valid) {
            #pragma unroll
            for (int ct = 0; ct < 8; ct++) {
                int col = ct * 16 + q * 4;
                float v0 = vals[ct][0], v1 = vals[ct][1];
                float v2 = vals[ct][2], v3 = vals[ct][3];
                if (RELU) {
                    v0 = fmaxf(v0, 0.f); v1 = fmaxf(v1, 0.f);
                    v2 = fmaxf(v2, 0.f); v3 = fmaxf(v3, 0.f);
                }
                if (OUTBF16) {
                    *(ushort4*)((bf16*)Cd + blockIdx.y * obStride + (size_t)row * ldc + col) =
                        pack4(v0, v1, v2, v3);
                } else {
                    *(float4*)((float*)Cd + blockIdx.y * obStride + (size_t)row * ldc + col) =
                        make_float4(v0, v1, v2, v3);
                }
            }
        }
    }
}

// ---------------- attention: 8 edges/wave, one head per lane ---------------
__device__ inline float dot8(uint4 a, uint4 b) {
    return blo(a.x) * blo(b.x) + bhi(a.x) * bhi(b.x)
         + blo(a.y) * blo(b.y) + bhi(a.y) * bhi(b.y)
         + blo(a.z) * blo(b.z) + bhi(a.z) * bhi(b.z)
         + blo(a.w) * blo(b.w) + bhi(a.w) * bhi(b.w);
}

__global__ __launch_bounds__(256) void attn_kernel(
    const bf16* __restrict__ Q, const bf16* __restrict__ K,
    const int* __restrict__ eidx, float* __restrict__ attn, int E_) {
    int gw = blockIdx.x * 4 + (threadIdx.x >> 6);
    int lane = threadIdx.x & 63;
    int e = gw * 8 + (lane >> 3);
    int h = lane & 7;
    bool v = e < E_;
    int src = v ? eidx[e] : 0;
    int dst = v ? eidx[E_ + e] : 0;
    const uint4* qp = (const uint4*)(Q + (size_t)dst * 128 + h * 16);
    const uint4* kp = (const uint4*)(K + (size_t)src * 128 + h * 16);
    uint4 q0 = qp[0], q1 = qp[1];
    uint4 k0 = kp[0], k1 = kp[1];
    float s = (dot8(q0, k0) + dot8(q1, k1)) * 0.25f;   // / sqrt(16)
    float mx = s;
    mx = fmaxf(mx, __shfl_xor(mx, 1));
    mx = fmaxf(mx, __shfl_xor(mx, 2));
    mx = fmaxf(mx, __shfl_xor(mx, 4));
    float ex = expf(s - mx);
    float sum = ex;
    sum += __shfl_xor(sum, 1);
    sum += __shfl_xor(sum, 2);
    sum += __shfl_xor(sum, 4);
    if (v) attn[(size_t)e * 8 + h] = ex / sum;   // coalesced: gw*64+lane
}

// ---------------- CSR build ------------------------------------------------
__global__ __launch_bounds__(256) void hist_kernel(
    const int* __restrict__ eidx, int* __restrict__ deg, int E_) {
    int e = blockIdx.x * 256 + threadIdx.x;
    if (e >= E_) return;
    atomicAdd(&deg[eidx[E_ + e]], 1);
}

__global__ __launch_bounds__(256) void alloc_kernel(
    const int* __restrict__ deg, int* __restrict__ start,
    int* __restrict__ cursor, int* __restrict__ counter, int n) {
    int i = blockIdx.x * 256 + threadIdx.x;
    if (i >= n) return;
    int d = deg[i];
    int s = atomicAdd(counter, d);
    start[i] = s;
    cursor[i] = s;
}

__global__ __launch_bounds__(256) void scatter_kernel(
    const int* __restrict__ eidx, int* __restrict__ cursor,
    int2* __restrict__ edata, int E_) {
    int e = blockIdx.x * 256 + threadIdx.x;
    if (e >= E_) return;
    int src = eidx[e];
    int dst = eidx[E_ + e];
    int pos = atomicAdd(&cursor[dst], 1);
    edata[pos] = make_int2(src, e);
}

// ---------------- aggregation: one wave/node, 2-way unrolled ---------------
__global__ __launch_bounds__(256) void aggr_kernel(
    const bf16* __restrict__ V, const float* __restrict__ attnW,
    const int* __restrict__ start, const int* __restrict__ deg,
    const int2* __restrict__ edata, bf16* __restrict__ ag, int n) {
    int wave = threadIdx.x >> 6;
    int lane = threadIdx.x & 63;
    int i = blockIdx.x * 4 + wave;
    if (i >= n) return;
    int s = start[i], d = deg[i];
    int h = lane >> 3;
    float ax = 0.f, ay = 0.f, bx = 0.f, by = 0.f;
    int j = s, e_ = s + d;
    for (; j + 2 <= e_; j += 2) {
        int2 e0 = edata[j], e1 = edata[j + 1];
        float a0 = attnW[(size_t)e0.y * 8 + h];
        float a1 = attnW[(size_t)e1.y * 8 + h];
        unsigned u0 = ((const unsigned*)(V + (size_t)e0.x * 128))[lane];
        unsigned u1 = ((const unsigned*)(V + (size_t)e1.x * 128))[lane];
        ax += a0 * blo(u0); ay += a0 * bhi(u0);
        bx += a1 * blo(u1); by += a1 * bhi(u1);
    }
    if (j < e_) {
        int2 e0 = edata[j];
        float a0 = attnW[(size_t)e0.y * 8 + h];
        unsigned u0 = ((const unsigned*)(V + (size_t)e0.x * 128))[lane];
        ax += a0 * blo(u0); ay += a0 * bhi(u0);
    }
    ax += bx; ay += by;
    __hip_bfloat162 o2;
    o2.x = __float2bfloat16(ax);
    o2.y = __float2bfloat16(ay);
    ((__hip_bfloat162*)(ag + (size_t)i * 128))[lane] = o2;
}

extern "C" void kernel_launch(void* const* d_in, const int* in_sizes, int n_in,
                              void* d_out, int out_size, void* d_ws, size_t ws_size,
                              hipStream_t stream) {
    const float* x   = (const float*)d_in[0];
    const int*  eidx = (const int*)d_in[1];
    const float* Wq = (const float*)d_in[2];  const float* bq = (const float*)d_in[3];
    const float* Wk = (const float*)d_in[4];  const float* bk = (const float*)d_in[5];
    const float* Wv = (const float*)d_in[6];  const float* bv = (const float*)d_in[7];
    const float* Wo = (const float*)d_in[8];  const float* bo = (const float*)d_in[9];
    const float* W1 = (const float*)d_in[10]; const float* b1 = (const float*)d_in[11];
    const float* W2 = (const float*)d_in[12]; const float* b2 = (const float*)d_in[13];
    const float* g1 = (const float*)d_in[14]; const float* be1 = (const float*)d_in[15];
    const float* g2 = (const float*)d_in[16]; const float* be2 = (const float*)d_in[17];
    float* out = (float*)d_out;

    int n  = in_sizes[0] / C_DIM;   // 100000
    int E_ = in_sizes[1] / 2;       // 600000
    size_t nf = (size_t)n * 128;

    // ---- workspace (~154 MB) ----
    bf16* Wt    = (bf16*)d_ws;                // 196608 bf16 transposed weights
    float* bqkv = (float*)(Wt + 196608);      // packed [bq|bk|bv]
    bf16* reg0  = (bf16*)(bqkv + 384);        // 4*nf: h1|Q|K|V ; u overlays all
    bf16* h1 = reg0;
    bf16* Qb = reg0 + nf;
    bf16* Kb = reg0 + 2 * nf;
    bf16* Vb = reg0 + 3 * nf;
    bf16* uB = reg0;                          // [N,512] bf16 (FFN intermediate)
    bf16* ag = reg0 + 4 * nf;                 // [N,128]
    char* r2 = (char*)(ag + nf);              // union region
    float* attnW = (float*)r2;                // [E,8] fp32
    int2* edata  = (int2*)(attnW + (size_t)E_ * 8);
    int*  ideg   = (int*)(edata + E_);
    int*  counter = ideg + n;
    int*  istart  = ideg + n + 1;
    int*  icursor = istart + n;
    bf16* h2 = (bf16*)r2;                     // overlays attnW/edata/CSR after aggr

    dim3 b256(256);
    dim3 lnGrid((n + 3) / 4);
    int rb = (n + 127) / 128;                 // 782
    dim3 eGrid8((E_ + 31) / 32);
    dim3 eGrid((E_ + 255) / 256);
    dim3 nGrid((n + 255) / 256);
    dim3 n1Grid((n + 1 + 255) / 256);
    dim3 n4Grid((n + 3) / 4);

    // weights -> bf16 transposed + packed bqkv (one dispatch)
    wconv_all<<<dim3(770), b256, 0, stream>>>(Wq, Wk, Wv, Wo, W1, W2, bq, bk, bv, Wt);
    // zero deg+counter
    zeroi_kernel<<<n1Grid, b256, 0, stream>>>(ideg, n + 1);
    // LN1: x -> h1
    ln_kernel<<<lnGrid, b256, 0, stream>>>(x, g1, be1, h1, n);
    // QKV: one dispatch, col-blocks -> Q|K|V buffers (obStride = nf)
    gemm_lds<true, false, false, 1><<<dim3(rb, 3), b256, 0, stream>>>(
        h1, 128, Wt, 128, bqkv, Qb, 128, nf, nullptr, 0, n, nullptr, nullptr, nullptr);
    // attention weights
    attn_kernel<<<eGrid8, b256, 0, stream>>>(Qb, Kb, eidx, attnW, E_);
    // CSR build
    hist_kernel<<<eGrid, b256, 0, stream>>>(eidx, ideg, E_);
    alloc_kernel<<<nGrid, b256, 0, stream>>>(ideg, istart, icursor, counter, n);
    scatter_kernel<<<eGrid, b256, 0, stream>>>(eidx, icursor, edata, E_);
    // aggregate into ag
    aggr_kernel<<<n4Grid, b256, 0, stream>>>(Vb, attnW, istart, ideg, edata, ag, n);
    // Wo + residual + fused LN2: x2 -> d_out (fp32), h2 (bf16, overlays r2)
    gemm_lds<false, false, true, 1><<<dim3(rb, 1), b256, 0, stream>>>(
        ag, 128, Wt + 49152, 128, bo, out, 128, 0, x, 128, n, g2, be2, h2);
    // FFN1: h2 @ W1 + b1, ReLU -> u [N,512] bf16 (overlays h1|Q|K|V, all dead)
    gemm_lds<true, true, false, 1><<<dim3(rb, 4), b256, 0, stream>>>(
        h2, 128, Wt + 65536, 128, b1, uB, 512, 128, nullptr, 0, n, nullptr, nullptr, nullptr);
    // FFN2: u @ W2 + b2 + x2 -> d_out (K=512 -> 4 k-tiles)
    gemm_lds<false, false, false, 4><<<dim3(rb, 1), b256, 0, stream>>>(
        uB, 512, Wt + 131072, 512, b2, out, 128, 0, out, 128, n, nullptr, nullptr, nullptr);
}

// Round 4
// 467.983 us; speedup vs baseline: 1.1029x; 1.1029x over previous
//
#include <hip/hip_runtime.h>
#include <hip/hip_bf16.h>

#define C_DIM 128
#define EPS_LN 1e-5f

typedef short bf16x8 __attribute__((ext_vector_type(8)));
typedef float f32x4  __attribute__((ext_vector_type(4)));
typedef __hip_bfloat16 bf16;

__device__ inline unsigned short f2bu(float f) {
    bf16 h = __float2bfloat16(f);
    return *reinterpret_cast<unsigned short*>(&h);
}
__device__ inline float blo(unsigned int u) { return __uint_as_float(u << 16); }
__device__ inline float bhi(unsigned int u) { return __uint_as_float(u & 0xffff0000u); }
__device__ inline ushort4 pack4(float a, float b, float c, float d) {
    ushort4 r; r.x = f2bu(a); r.y = f2bu(b); r.z = f2bu(c); r.w = f2bu(d); return r;
}

// async global->LDS DMA, 16B per lane. LDS dest is WAVE-UNIFORM base;
// HW writes lane l's 16B at base + l*16. Global src is per-lane.
__device__ inline void async_copy16(const bf16* g, bf16* s) {
    __builtin_amdgcn_global_load_lds(
        (const __attribute__((address_space(1))) unsigned int*)g,
        (__attribute__((address_space(3))) unsigned int*)s,
        16, 0, 0);
}

// ---------------- weights convert+transpose + bias pack, ONE dispatch ------
// dst (bf16): Wqt|Wkt|Wvt|Wot (4x 128*128) | Wt1[512][128] | Wt2[128][512]
// then packed fp32 bqkv[384] right after.
__global__ __launch_bounds__(256) void wconv_all(
    const float* __restrict__ Wq, const float* __restrict__ Wk,
    const float* __restrict__ Wv, const float* __restrict__ Wo,
    const float* __restrict__ W1, const float* __restrict__ W2,
    const float* __restrict__ bq, const float* __restrict__ bk,
    const float* __restrict__ bv, bf16* __restrict__ dst) {
    int idx = blockIdx.x * 256 + threadIdx.x;
    if (idx < 65536) {                       // four 128x128 weights
        int r = idx >> 14, o = idx & 16383;
        int k = o >> 7, nn = o & 127;
        const float* W = (r == 0) ? Wq : (r == 1) ? Wk : (r == 2) ? Wv : Wo;
        dst[(r << 14) + nn * 128 + k] = __float2bfloat16(W[o]);
    } else if (idx < 131072) {               // W1 [128,512] -> Wt1[n][k]
        int o = idx - 65536;
        int k = o >> 9, nn = o & 511;
        dst[65536 + nn * 128 + k] = __float2bfloat16(W1[o]);
    } else if (idx < 196608) {               // W2 [512,128] -> Wt2[n][k]
        int o = idx - 131072;
        int k = o >> 7, nn = o & 127;
        dst[131072 + nn * 512 + k] = __float2bfloat16(W2[o]);
    } else if (idx < 196992) {               // packed bqkv[384] fp32
        int j = idx - 196608;
        int grp = j >> 7, col = j & 127;
        const float* bp = (grp == 0) ? bq : (grp == 1) ? bk : bv;
        ((float*)(dst + 196608))[j] = bp[col];
    }
}

__global__ __launch_bounds__(256) void zeroi_kernel(int* __restrict__ p, int n) {
    int i = blockIdx.x * 256 + threadIdx.x;
    if (i < n) p[i] = 0;
}

// ---------------- LayerNorm fp32 -> bf16, one wave per row -----------------
__global__ __launch_bounds__(256) void ln_kernel(
    const float* __restrict__ x, const float* __restrict__ g,
    const float* __restrict__ b, bf16* __restrict__ out, int n) {
    int wave = threadIdx.x >> 6;
    int lane = threadIdx.x & 63;
    int row = blockIdx.x * 4 + wave;
    if (row >= n) return;
    float2 v = ((const float2*)(x + (size_t)row * C_DIM))[lane];
    float s  = v.x + v.y;
    float ss = v.x * v.x + v.y * v.y;
    #pragma unroll
    for (int o = 1; o < 64; o <<= 1) {
        s  += __shfl_xor(s, o);
        ss += __shfl_xor(ss, o);
    }
    float mu  = s * (1.0f / C_DIM);
    float var = ss * (1.0f / C_DIM) - mu * mu;
    float rs  = rsqrtf(var + EPS_LN);
    float2 gg = ((const float2*)g)[lane];
    float2 bb = ((const float2*)b)[lane];
    __hip_bfloat162 o2;
    o2.x = __float2bfloat16((v.x - mu) * rs * gg.x + bb.x);
    o2.y = __float2bfloat16((v.y - mu) * rs * gg.y + bb.y);
    ((__hip_bfloat162*)(out + (size_t)row * C_DIM))[lane] = o2;
}

// ---------------- LDS-staged MFMA GEMM (global_load_lds + XOR swizzle) -----
// Block: 128 rows x 128 cols of C; 4 waves, each 32 rows x 128 cols.
// A [M,lda] bf16 row-major; Bt [Ncols][Kfull] bf16 (row = output col).
// Staging: async_copy16, wave-uniform LDS base (linear [128][128]), per-lane
// global src pre-swizzled: LDS slot s of row r holds global slot s^(r&7).
// Reads use ((ks*4+q)^(m&7))<<3 -> bank-uniform (2 lanes/bank, free).
// Tail: clamp source row to M-1 (garbage lands only in C rows >= M, masked).
// NOTE round-3 lesson: A direct-to-reg (64B segments) over-fetches HBM and
// regresses despite 2x occupancy -- keep BOTH operands on the 1KB-contiguous
// DMA path.
// Operand-swapped mfma(bf, af, acc): lane(m,q) reg r = C[row0+..+m][ct*16+q*4+r].
template<bool OUTBF16, bool RELU, bool FUSE_LN, int KSTEPS>
__global__ __launch_bounds__(256) void gemm_lds(
    const bf16* __restrict__ A, int lda,
    const bf16* __restrict__ Bt, int Kfull,
    const float* __restrict__ biasBase,
    void* __restrict__ Cd, int ldc, size_t obStride,
    const float* __restrict__ resid, int ldres,
    int M,
    const float* __restrict__ g, const float* __restrict__ be,
    bf16* __restrict__ h2) {
    __shared__ bf16 As[128][128];
    __shared__ bf16 Bs[128][128];
    int tid  = threadIdx.x;
    int lane = tid & 63;
    int w    = tid >> 6;
    int m = lane & 15, q = lane >> 4;
    int row0 = blockIdx.x * 128;
    const bf16* Bbase = Bt + (size_t)blockIdx.y * 128 * Kfull;

    f32x4 acc[2][8];
    #pragma unroll
    for (int rt = 0; rt < 2; rt++)
        #pragma unroll
        for (int ct = 0; ct < 8; ct++) acc[rt][ct] = (f32x4){0.f, 0.f, 0.f, 0.f};

    int rsub  = lane >> 4;      // 0..3: this lane's dest row within a 4-row DMA call
    int cslot = lane & 15;      // this lane's 16B slot within the row

    for (int kt = 0; kt < KSTEPS; kt++) {
        // stage A+B tiles [128][128] via 8+8 async DMA calls per wave
        #pragma unroll
        for (int i = 0; i < 8; i++) {
            int arow = w * 32 + i * 4 + rsub;                 // dest row 0..127
            int scol = (cslot ^ (arow & 7)) << 3;             // swizzled src slot (elems)
            int garow = row0 + arow;
            if (garow > M - 1) garow = M - 1;                 // tail clamp
            async_copy16(A + (size_t)garow * lda + kt * 128 + scol, &As[w * 32 + i * 4][0]);
            async_copy16(Bbase + (size_t)arow * Kfull + kt * 128 + scol, &Bs[w * 32 + i * 4][0]);
        }
        __syncthreads();
        #pragma unroll
        for (int ks = 0; ks < 4; ks++) {
            int sofs = ((ks * 4 + q) ^ (m & 7)) << 3;         // swizzled read offset
            bf16x8 af0 = *(const bf16x8*)&As[w * 32 + m][sofs];
            bf16x8 af1 = *(const bf16x8*)&As[w * 32 + 16 + m][sofs];
            #pragma unroll
            for (int ct = 0; ct < 8; ct++) {
                bf16x8 bf = *(const bf16x8*)&Bs[ct * 16 + m][sofs];
                acc[0][ct] = __builtin_amdgcn_mfma_f32_16x16x32_bf16(bf, af0, acc[0][ct], 0, 0, 0);
                acc[1][ct] = __builtin_amdgcn_mfma_f32_16x16x32_bf16(bf, af1, acc[1][ct], 0, 0, 0);
            }
        }
        if (kt + 1 < KSTEPS) __syncthreads();
    }

    // ---- epilogue ----
    #pragma unroll
    for (int rt = 0; rt < 2; rt++) {
        int row = row0 + w * 32 + rt * 16 + m;
        bool valid = row < M;
        float vals[8][4];
        #pragma unroll
        for (int ct = 0; ct < 8; ct++) {
            int col = ct * 16 + q * 4;
            float4 bv = make_float4(0.f, 0.f, 0.f, 0.f);
            if (biasBase) bv = *(const float4*)(biasBase + blockIdx.y * 128 + col);
            float4 rv = make_float4(0.f, 0.f, 0.f, 0.f);
            if (resid && valid) rv = *(const float4*)(resid + (size_t)row * ldres + col);
            vals[ct][0] = acc[rt][ct][0] + bv.x + rv.x;
            vals[ct][1] = acc[rt][ct][1] + bv.y + rv.y;
            vals[ct][2] = acc[rt][ct][2] + bv.z + rv.z;
            vals[ct][3] = acc[rt][ct][3] + bv.w + rv.w;
        }
        if (FUSE_LN) {
            // row spans lanes {m, m+16, m+32, m+48}: reduce over q via xor 16,32
            float s1 = 0.f, s2 = 0.f;
            #pragma unroll
            for (int ct = 0; ct < 8; ct++)
                #pragma unroll
                for (int r = 0; r < 4; r++) { s1 += vals[ct][r]; s2 += vals[ct][r] * vals[ct][r]; }
            s1 += __shfl_xor(s1, 16); s1 += __shfl_xor(s1, 32);
            s2 += __shfl_xor(s2, 16); s2 += __shfl_xor(s2, 32);
            float mu  = s1 * (1.0f / 128.f);
            float var = s2 * (1.0f / 128.f) - mu * mu;
            float rs  = rsqrtf(var + EPS_LN);
            if (valid) {
                #pragma unroll
                for (int ct = 0; ct < 8; ct++) {
                    int col = ct * 16 + q * 4;
                    *(float4*)((float*)Cd + (size_t)row * ldc + col) =
                        make_float4(vals[ct][0], vals[ct][1], vals[ct][2], vals[ct][3]);
                    float4 gg = *(const float4*)(g + col);
                    float4 bb = *(const float4*)(be + col);
                    *(ushort4*)(h2 + (size_t)row * 128 + col) =
                        pack4((vals[ct][0] - mu) * rs * gg.x + bb.x,
                              (vals[ct][1] - mu) * rs * gg.y + bb.y,
                              (vals[ct][2] - mu) * rs * gg.z + bb.z,
                              (vals[ct][3] - mu) * rs * gg.w + bb.w);
                }
            }
        } else if (valid) {
            #pragma unroll
            for (int ct = 0; ct < 8; ct++) {
                int col = ct * 16 + q * 4;
                float v0 = vals[ct][0], v1 = vals[ct][1];
                float v2 = vals[ct][2], v3 = vals[ct][3];
                if (RELU) {
                    v0 = fmaxf(v0, 0.f); v1 = fmaxf(v1, 0.f);
                    v2 = fmaxf(v2, 0.f); v3 = fmaxf(v3, 0.f);
                }
                if (OUTBF16) {
                    *(ushort4*)((bf16*)Cd + blockIdx.y * obStride + (size_t)row * ldc + col) =
                        pack4(v0, v1, v2, v3);
                } else {
                    *(float4*)((float*)Cd + blockIdx.y * obStride + (size_t)row * ldc + col) =
                        make_float4(v0, v1, v2, v3);
                }
            }
        }
    }
}

// ---------------- CSR build ------------------------------------------------
__global__ __launch_bounds__(256) void hist_kernel(
    const int* __restrict__ eidx, int* __restrict__ deg, int E_) {
    int e = blockIdx.x * 256 + threadIdx.x;
    if (e >= E_) return;
    atomicAdd(&deg[eidx[E_ + e]], 1);
}

__global__ __launch_bounds__(256) void alloc_kernel(
    const int* __restrict__ deg, int* __restrict__ start,
    int* __restrict__ cursor, int* __restrict__ counter, int n) {
    int i = blockIdx.x * 256 + threadIdx.x;
    if (i >= n) return;
    int d = deg[i];
    int s = atomicAdd(counter, d);
    start[i] = s;
    cursor[i] = s;
}

__global__ __launch_bounds__(256) void scatter_kernel(
    const int* __restrict__ eidx, int* __restrict__ cursor,
    int* __restrict__ esrc, int E_) {
    int e = blockIdx.x * 256 + threadIdx.x;
    if (e >= E_) return;
    int src = eidx[e];
    int dst = eidx[E_ + e];
    int pos = atomicAdd(&cursor[dst], 1);
    esrc[pos] = src;
}

// ---------- fused attention + aggregation: one wave per node ---------------
// Softmax is over HEADS per edge -> weight depends only on the edge, so it
// can be computed inline. Lane holds 2 channels (cols 2*lane, 2*lane+1);
// head h = lane>>3 spans lanes 8h..8h+7. Per edge: dot via 8-lane tree
// (xor 1,2,4), head max/sum via cross-group tree (xor 8,16,32).
// Kills the separate attn pass (600K Q/K gathers + 19.2MB attnW round-trip).
__global__ __launch_bounds__(256) void attn_aggr_kernel(
    const bf16* __restrict__ Q, const bf16* __restrict__ K,
    const bf16* __restrict__ V,
    const int* __restrict__ start, const int* __restrict__ deg,
    const int* __restrict__ esrc, bf16* __restrict__ ag, int n) {
    int wave = threadIdx.x >> 6;
    int lane = threadIdx.x & 63;
    int i = blockIdx.x * 4 + wave;
    if (i >= n) return;
    int s = start[i], d = deg[i];
    unsigned qu = ((const unsigned*)(Q + (size_t)i * 128))[lane];
    float qx = blo(qu), qy = bhi(qu);
    float ax = 0.f, ay = 0.f;
    int j = s, e_ = s + d;
    for (; j + 2 <= e_; j += 2) {
        int s0 = esrc[j], s1 = esrc[j + 1];
        unsigned k0 = ((const unsigned*)(K + (size_t)s0 * 128))[lane];
        unsigned k1 = ((const unsigned*)(K + (size_t)s1 * 128))[lane];
        unsigned v0 = ((const unsigned*)(V + (size_t)s0 * 128))[lane];
        unsigned v1 = ((const unsigned*)(V + (size_t)s1 * 128))[lane];
        float p0 = qx * blo(k0) + qy * bhi(k0);
        float p1 = qx * blo(k1) + qy * bhi(k1);
        p0 += __shfl_xor(p0, 1); p1 += __shfl_xor(p1, 1);
        p0 += __shfl_xor(p0, 2); p1 += __shfl_xor(p1, 2);
        p0 += __shfl_xor(p0, 4); p1 += __shfl_xor(p1, 4);
        p0 *= 0.25f; p1 *= 0.25f;                       // / sqrt(16)
        float m0 = fmaxf(p0, __shfl_xor(p0, 8));
        float m1 = fmaxf(p1, __shfl_xor(p1, 8));
        m0 = fmaxf(m0, __shfl_xor(m0, 16)); m1 = fmaxf(m1, __shfl_xor(m1, 16));
        m0 = fmaxf(m0, __shfl_xor(m0, 32)); m1 = fmaxf(m1, __shfl_xor(m1, 32));
        float e0 = expf(p0 - m0), e1 = expf(p1 - m1);
        float t0 = e0 + __shfl_xor(e0, 8);
        float t1 = e1 + __shfl_xor(e1, 8);
        t0 += __shfl_xor(t0, 16); t1 += __shfl_xor(t1, 16);
        t0 += __shfl_xor(t0, 32); t1 += __shfl_xor(t1, 32);
        float a0 = e0 / t0, a1 = e1 / t1;
        ax += a0 * blo(v0) + a1 * blo(v1);
        ay += a0 * bhi(v0) + a1 * bhi(v1);
    }
    if (j < e_) {
        int s0 = esrc[j];
        unsigned k0 = ((const unsigned*)(K + (size_t)s0 * 128))[lane];
        unsigned v0 = ((const unsigned*)(V + (size_t)s0 * 128))[lane];
        float p0 = qx * blo(k0) + qy * bhi(k0);
        p0 += __shfl_xor(p0, 1);
        p0 += __shfl_xor(p0, 2);
        p0 += __shfl_xor(p0, 4);
        p0 *= 0.25f;
        float m0 = fmaxf(p0, __shfl_xor(p0, 8));
        m0 = fmaxf(m0, __shfl_xor(m0, 16));
        m0 = fmaxf(m0, __shfl_xor(m0, 32));
        float e0 = expf(p0 - m0);
        float t0 = e0 + __shfl_xor(e0, 8);
        t0 += __shfl_xor(t0, 16);
        t0 += __shfl_xor(t0, 32);
        float a0 = e0 / t0;
        ax += a0 * blo(v0);
        ay += a0 * bhi(v0);
    }
    __hip_bfloat162 o2;
    o2.x = __float2bfloat16(ax);
    o2.y = __float2bfloat16(ay);
    ((__hip_bfloat162*)(ag + (size_t)i * 128))[lane] = o2;
}

extern "C" void kernel_launch(void* const* d_in, const int* in_sizes, int n_in,
                              void* d_out, int out_size, void* d_ws, size_t ws_size,
                              hipStream_t stream) {
    const float* x   = (const float*)d_in[0];
    const int*  eidx = (const int*)d_in[1];
    const float* Wq = (const float*)d_in[2];  const float* bq = (const float*)d_in[3];
    const float* Wk = (const float*)d_in[4];  const float* bk = (const float*)d_in[5];
    const float* Wv = (const float*)d_in[6];  const float* bv = (const float*)d_in[7];
    const float* Wo = (const float*)d_in[8];  const float* bo = (const float*)d_in[9];
    const float* W1 = (const float*)d_in[10]; const float* b1 = (const float*)d_in[11];
    const float* W2 = (const float*)d_in[12]; const float* b2 = (const float*)d_in[13];
    const float* g1 = (const float*)d_in[14]; const float* be1 = (const float*)d_in[15];
    const float* g2 = (const float*)d_in[16]; const float* be2 = (const float*)d_in[17];
    float* out = (float*)d_out;

    int n  = in_sizes[0] / C_DIM;   // 100000
    int E_ = in_sizes[1] / 2;       // 600000
    size_t nf = (size_t)n * 128;

    // ---- workspace ----
    bf16* Wt    = (bf16*)d_ws;                // 196608 bf16 transposed weights
    float* bqkv = (float*)(Wt + 196608);      // packed [bq|bk|bv]
    bf16* reg0  = (bf16*)(bqkv + 384);        // 4*nf: h1|Q|K|V ; u overlays all
    bf16* h1 = reg0;
    bf16* Qb = reg0 + nf;
    bf16* Kb = reg0 + 2 * nf;
    bf16* Vb = reg0 + 3 * nf;
    bf16* uB = reg0;                          // [N,512] bf16 (FFN intermediate)
    bf16* ag = reg0 + 4 * nf;                 // [N,128]
    char* r2 = (char*)(ag + nf);              // union region
    int*  esrc   = (int*)r2;                  // [E] CSR-ordered source ids
    int*  ideg   = esrc + E_;
    int*  counter = ideg + n;
    int*  istart  = ideg + n + 1;
    int*  icursor = istart + n;
    bf16* h2 = (bf16*)r2;                     // overlays esrc/CSR after attn_aggr

    dim3 b256(256);
    dim3 lnGrid((n + 3) / 4);
    int rb = (n + 127) / 128;                 // 782
    dim3 eGrid((E_ + 255) / 256);
    dim3 nGrid((n + 255) / 256);
    dim3 n1Grid((n + 1 + 255) / 256);
    dim3 n4Grid((n + 3) / 4);

    // weights -> bf16 transposed + packed bqkv (one dispatch)
    wconv_all<<<dim3(770), b256, 0, stream>>>(Wq, Wk, Wv, Wo, W1, W2, bq, bk, bv, Wt);
    // zero deg+counter
    zeroi_kernel<<<n1Grid, b256, 0, stream>>>(ideg, n + 1);
    // LN1: x -> h1
    ln_kernel<<<lnGrid, b256, 0, stream>>>(x, g1, be1, h1, n);
    // QKV: one dispatch, col-blocks -> Q|K|V buffers (obStride = nf)
    gemm_lds<true, false, false, 1><<<dim3(rb, 3), b256, 0, stream>>>(
        h1, 128, Wt, 128, bqkv, Qb, 128, nf, nullptr, 0, n, nullptr, nullptr, nullptr);
    // CSR build
    hist_kernel<<<eGrid, b256, 0, stream>>>(eidx, ideg, E_);
    alloc_kernel<<<nGrid, b256, 0, stream>>>(ideg, istart, icursor, counter, n);
    scatter_kernel<<<eGrid, b256, 0, stream>>>(eidx, icursor, esrc, E_);
    // fused attention + aggregation into ag
    attn_aggr_kernel<<<n4Grid, b256, 0, stream>>>(Qb, Kb, Vb, istart, ideg, esrc, ag, n);
    // Wo + residual + fused LN2: x2 -> d_out (fp32), h2 (bf16, overlays r2)
    gemm_lds<false, false, true, 1><<<dim3(rb, 1), b256, 0, stream>>>(
        ag, 128, Wt + 49152, 128, bo, out, 128, 0, x, 128, n, g2, be2, h2);
    // FFN1: h2 @ W1 + b1, ReLU -> u [N,512] bf16 (overlays h1|Q|K|V, all dead)
    gemm_lds<true, true, false, 1><<<dim3(rb, 4), b256, 0, stream>>>(
        h2, 128, Wt + 65536, 128, b1, uB, 512, 128, nullptr, 0, n, nullptr, nullptr, nullptr);
    // FFN2: u @ W2 + b2 + x2 -> d_out (K=512 -> 4 k-tiles)
    gemm_lds<false, false, false, 4><<<dim3(rb, 1), b256, 0, stream>>>(
        uB, 512, Wt + 131072, 512, b2, out, 128, 0, out, 128, n, nullptr, nullptr, nullptr);
}

// Round 5
// 462.670 us; speedup vs baseline: 1.1156x; 1.0115x over previous
//
#include <hip/hip_runtime.h>
#include <hip/hip_bf16.h>

#define C_DIM 128
#define EPS_LN 1e-5f

typedef short bf16x8 __attribute__((ext_vector_type(8)));
typedef float f32x4  __attribute__((ext_vector_type(4)));
typedef __hip_bfloat16 bf16;

__device__ inline unsigned short f2bu(float f) {
    bf16 h = __float2bfloat16(f);
    return *reinterpret_cast<unsigned short*>(&h);
}
__device__ inline float blo(unsigned int u) { return __uint_as_float(u << 16); }
__device__ inline float bhi(unsigned int u) { return __uint_as_float(u & 0xffff0000u); }
__device__ inline ushort4 pack4(float a, float b, float c, float d) {
    ushort4 r; r.x = f2bu(a); r.y = f2bu(b); r.z = f2bu(c); r.w = f2bu(d); return r;
}

// async global->LDS DMA, 16B per lane. LDS dest is WAVE-UNIFORM base;
// HW writes lane l's 16B at base + l*16. Global src is per-lane.
__device__ inline void async_copy16(const bf16* g, bf16* s) {
    __builtin_amdgcn_global_load_lds(
        (const __attribute__((address_space(1))) unsigned int*)g,
        (__attribute__((address_space(3))) unsigned int*)s,
        16, 0, 0);
}

// ---------------- weights convert+transpose + bias pack, ONE dispatch ------
// dst (bf16): Wqt|Wkt|Wvt|Wot (4x 128*128) | Wt1[512][128] | Wt2[128][512]
// then packed fp32 bqkv[384] right after.
__global__ __launch_bounds__(256) void wconv_all(
    const float* __restrict__ Wq, const float* __restrict__ Wk,
    const float* __restrict__ Wv, const float* __restrict__ Wo,
    const float* __restrict__ W1, const float* __restrict__ W2,
    const float* __restrict__ bq, const float* __restrict__ bk,
    const float* __restrict__ bv, bf16* __restrict__ dst) {
    int idx = blockIdx.x * 256 + threadIdx.x;
    if (idx < 65536) {                       // four 128x128 weights
        int r = idx >> 14, o = idx & 16383;
        int k = o >> 7, nn = o & 127;
        const float* W = (r == 0) ? Wq : (r == 1) ? Wk : (r == 2) ? Wv : Wo;
        dst[(r << 14) + nn * 128 + k] = __float2bfloat16(W[o]);
    } else if (idx < 131072) {               // W1 [128,512] -> Wt1[n][k]
        int o = idx - 65536;
        int k = o >> 9, nn = o & 511;
        dst[65536 + nn * 128 + k] = __float2bfloat16(W1[o]);
    } else if (idx < 196608) {               // W2 [512,128] -> Wt2[n][k]
        int o = idx - 131072;
        int k = o >> 7, nn = o & 127;
        dst[131072 + nn * 512 + k] = __float2bfloat16(W2[o]);
    } else if (idx < 196992) {               // packed bqkv[384] fp32
        int j = idx - 196608;
        int grp = j >> 7, col = j & 127;
        const float* bp = (grp == 0) ? bq : (grp == 1) ? bk : bv;
        ((float*)(dst + 196608))[j] = bp[col];
    }
}

__global__ __launch_bounds__(256) void zeroi_kernel(int* __restrict__ p, int n) {
    int i = blockIdx.x * 256 + threadIdx.x;
    if (i < n) p[i] = 0;
}

// ---------------- LayerNorm fp32 -> bf16, one wave per row -----------------
__global__ __launch_bounds__(256) void ln_kernel(
    const float* __restrict__ x, const float* __restrict__ g,
    const float* __restrict__ b, bf16* __restrict__ out, int n) {
    int wave = threadIdx.x >> 6;
    int lane = threadIdx.x & 63;
    int row = blockIdx.x * 4 + wave;
    if (row >= n) return;
    float2 v = ((const float2*)(x + (size_t)row * C_DIM))[lane];
    float s  = v.x + v.y;
    float ss = v.x * v.x + v.y * v.y;
    #pragma unroll
    for (int o = 1; o < 64; o <<= 1) {
        s  += __shfl_xor(s, o);
        ss += __shfl_xor(ss, o);
    }
    float mu  = s * (1.0f / C_DIM);
    float var = ss * (1.0f / C_DIM) - mu * mu;
    float rs  = rsqrtf(var + EPS_LN);
    float2 gg = ((const float2*)g)[lane];
    float2 bb = ((const float2*)b)[lane];
    __hip_bfloat162 o2;
    o2.x = __float2bfloat16((v.x - mu) * rs * gg.x + bb.x);
    o2.y = __float2bfloat16((v.y - mu) * rs * gg.y + bb.y);
    ((__hip_bfloat162*)(out + (size_t)row * C_DIM))[lane] = o2;
}

// ---------------- LDS-staged MFMA GEMM (global_load_lds + XOR swizzle) -----
// Block: 128 rows x 128 cols of C; 4 waves, each 32 rows x 128 cols.
// A [M,lda] bf16 row-major; Bt [Ncols][Kfull] bf16 (row = output col).
// Staging: async_copy16, wave-uniform LDS base (linear [128][128]), per-lane
// global src pre-swizzled: LDS slot s of row r holds global slot s^(r&7).
// Reads use ((ks*4+q)^(m&7))<<3 -> bank-uniform (2 lanes/bank, free).
// Tail: clamp source row to M-1 (garbage lands only in C rows >= M, masked).
// NOTE round-3 lesson: A direct-to-reg (64B segments) over-fetches HBM and
// regresses despite 2x occupancy -- keep BOTH operands on the 1KB-contiguous
// DMA path.
// Operand-swapped mfma(bf, af, acc): lane(m,q) reg r = C[row0+..+m][ct*16+q*4+r].
template<bool OUTBF16, bool RELU, bool FUSE_LN, int KSTEPS>
__global__ __launch_bounds__(256) void gemm_lds(
    const bf16* __restrict__ A, int lda,
    const bf16* __restrict__ Bt, int Kfull,
    const float* __restrict__ biasBase,
    void* __restrict__ Cd, int ldc, size_t obStride,
    const float* __restrict__ resid, int ldres,
    int M,
    const float* __restrict__ g, const float* __restrict__ be,
    bf16* __restrict__ h2) {
    __shared__ bf16 As[128][128];
    __shared__ bf16 Bs[128][128];
    int tid  = threadIdx.x;
    int lane = tid & 63;
    int w    = tid >> 6;
    int m = lane & 15, q = lane >> 4;
    int row0 = blockIdx.x * 128;
    const bf16* Bbase = Bt + (size_t)blockIdx.y * 128 * Kfull;

    f32x4 acc[2][8];
    #pragma unroll
    for (int rt = 0; rt < 2; rt++)
        #pragma unroll
        for (int ct = 0; ct < 8; ct++) acc[rt][ct] = (f32x4){0.f, 0.f, 0.f, 0.f};

    int rsub  = lane >> 4;      // 0..3: this lane's dest row within a 4-row DMA call
    int cslot = lane & 15;      // this lane's 16B slot within the row

    for (int kt = 0; kt < KSTEPS; kt++) {
        // stage A+B tiles [128][128] via 8+8 async DMA calls per wave
        #pragma unroll
        for (int i = 0; i < 8; i++) {
            int arow = w * 32 + i * 4 + rsub;                 // dest row 0..127
            int scol = (cslot ^ (arow & 7)) << 3;             // swizzled src slot (elems)
            int garow = row0 + arow;
            if (garow > M - 1) garow = M - 1;                 // tail clamp
            async_copy16(A + (size_t)garow * lda + kt * 128 + scol, &As[w * 32 + i * 4][0]);
            async_copy16(Bbase + (size_t)arow * Kfull + kt * 128 + scol, &Bs[w * 32 + i * 4][0]);
        }
        __syncthreads();
        #pragma unroll
        for (int ks = 0; ks < 4; ks++) {
            int sofs = ((ks * 4 + q) ^ (m & 7)) << 3;         // swizzled read offset
            bf16x8 af0 = *(const bf16x8*)&As[w * 32 + m][sofs];
            bf16x8 af1 = *(const bf16x8*)&As[w * 32 + 16 + m][sofs];
            #pragma unroll
            for (int ct = 0; ct < 8; ct++) {
                bf16x8 bf = *(const bf16x8*)&Bs[ct * 16 + m][sofs];
                acc[0][ct] = __builtin_amdgcn_mfma_f32_16x16x32_bf16(bf, af0, acc[0][ct], 0, 0, 0);
                acc[1][ct] = __builtin_amdgcn_mfma_f32_16x16x32_bf16(bf, af1, acc[1][ct], 0, 0, 0);
            }
        }
        if (kt + 1 < KSTEPS) __syncthreads();
    }

    // ---- epilogue ----
    #pragma unroll
    for (int rt = 0; rt < 2; rt++) {
        int row = row0 + w * 32 + rt * 16 + m;
        bool valid = row < M;
        float vals[8][4];
        #pragma unroll
        for (int ct = 0; ct < 8; ct++) {
            int col = ct * 16 + q * 4;
            float4 bv = make_float4(0.f, 0.f, 0.f, 0.f);
            if (biasBase) bv = *(const float4*)(biasBase + blockIdx.y * 128 + col);
            float4 rv = make_float4(0.f, 0.f, 0.f, 0.f);
            if (resid && valid) rv = *(const float4*)(resid + (size_t)row * ldres + col);
            vals[ct][0] = acc[rt][ct][0] + bv.x + rv.x;
            vals[ct][1] = acc[rt][ct][1] + bv.y + rv.y;
            vals[ct][2] = acc[rt][ct][2] + bv.z + rv.z;
            vals[ct][3] = acc[rt][ct][3] + bv.w + rv.w;
        }
        if (FUSE_LN) {
            // row spans lanes {m, m+16, m+32, m+48}: reduce over q via xor 16,32
            float s1 = 0.f, s2 = 0.f;
            #pragma unroll
            for (int ct = 0; ct < 8; ct++)
                #pragma unroll
                for (int r = 0; r < 4; r++) { s1 += vals[ct][r]; s2 += vals[ct][r] * vals[ct][r]; }
            s1 += __shfl_xor(s1, 16); s1 += __shfl_xor(s1, 32);
            s2 += __shfl_xor(s2, 16); s2 += __shfl_xor(s2, 32);
            float mu  = s1 * (1.0f / 128.f);
            float var = s2 * (1.0f / 128.f) - mu * mu;
            float rs  = rsqrtf(var + EPS_LN);
            if (valid) {
                #pragma unroll
                for (int ct = 0; ct < 8; ct++) {
                    int col = ct * 16 + q * 4;
                    *(float4*)((float*)Cd + (size_t)row * ldc + col) =
                        make_float4(vals[ct][0], vals[ct][1], vals[ct][2], vals[ct][3]);
                    float4 gg = *(const float4*)(g + col);
                    float4 bb = *(const float4*)(be + col);
                    *(ushort4*)(h2 + (size_t)row * 128 + col) =
                        pack4((vals[ct][0] - mu) * rs * gg.x + bb.x,
                              (vals[ct][1] - mu) * rs * gg.y + bb.y,
                              (vals[ct][2] - mu) * rs * gg.z + bb.z,
                              (vals[ct][3] - mu) * rs * gg.w + bb.w);
                }
            }
        } else if (valid) {
            #pragma unroll
            for (int ct = 0; ct < 8; ct++) {
                int col = ct * 16 + q * 4;
                float v0 = vals[ct][0], v1 = vals[ct][1];
                float v2 = vals[ct][2], v3 = vals[ct][3];
                if (RELU) {
                    v0 = fmaxf(v0, 0.f); v1 = fmaxf(v1, 0.f);
                    v2 = fmaxf(v2, 0.f); v3 = fmaxf(v3, 0.f);
                }
                if (OUTBF16) {
                    *(ushort4*)((bf16*)Cd + blockIdx.y * obStride + (size_t)row * ldc + col) =
                        pack4(v0, v1, v2, v3);
                } else {
                    *(float4*)((float*)Cd + blockIdx.y * obStride + (size_t)row * ldc + col) =
                        make_float4(v0, v1, v2, v3);
                }
            }
        }
    }
}

// ---------------- CSR build ------------------------------------------------
__global__ __launch_bounds__(256) void hist_kernel(
    const int* __restrict__ eidx, int* __restrict__ deg, int E_) {
    int e = blockIdx.x * 256 + threadIdx.x;
    if (e >= E_) return;
    atomicAdd(&deg[eidx[E_ + e]], 1);
}

__global__ __launch_bounds__(256) void alloc_kernel(
    const int* __restrict__ deg, int* __restrict__ start,
    int* __restrict__ cursor, int* __restrict__ counter, int n) {
    int i = blockIdx.x * 256 + threadIdx.x;
    if (i >= n) return;
    int d = deg[i];
    int s = atomicAdd(counter, d);
    start[i] = s;
    cursor[i] = s;
}

__global__ __launch_bounds__(256) void scatter_kernel(
    const int* __restrict__ eidx, int* __restrict__ cursor,
    int* __restrict__ esrc, int E_) {
    int e = blockIdx.x * 256 + threadIdx.x;
    if (e >= E_) return;
    int src = eidx[e];
    int dst = eidx[E_ + e];
    int pos = atomicAdd(&cursor[dst], 1);
    esrc[pos] = src;
}

// ---------- fused attention + aggregation: one wave per node ---------------
// Round-5 restructure: 8 edges per wave iteration, two phases.
// Phase 1 (no lane redundancy): 8 groups x 8 lanes; group g = edge j+g,
// lane l in group = head l (channels 16l..16l+15 = 2 x uint4 of K). Full
// 16-ch dot per lane, NO shuffles; softmax across heads = across the 8
// group lanes (xor 1,2,4) -> 6 shuffles per 8 edges (was 9 per edge).
// exp2f with folded 0.25*log2e scale (monotonic -> same argmax); fast div.
// Phase 2: per edge, 1 shfl for weight + 1 shfl for src, coalesced 256B
// V-row accumulate (lane holds channels 2*lane,2*lane+1; head = lane>>3).
// Tail: invalid groups compute garbage weights phase 2 never reads
// (uniform j+e<end guard).
__device__ inline float dot8f(uint4 a, uint4 b) {
    return blo(a.x) * blo(b.x) + bhi(a.x) * bhi(b.x)
         + blo(a.y) * blo(b.y) + bhi(a.y) * bhi(b.y)
         + blo(a.z) * blo(b.z) + bhi(a.z) * bhi(b.z)
         + blo(a.w) * blo(b.w) + bhi(a.w) * bhi(b.w);
}

__global__ __launch_bounds__(256) void attn_aggr_kernel(
    const bf16* __restrict__ Q, const bf16* __restrict__ K,
    const bf16* __restrict__ V,
    const int* __restrict__ start, const int* __restrict__ deg,
    const int* __restrict__ esrc, bf16* __restrict__ ag, int n) {
    int wave = threadIdx.x >> 6;
    int lane = threadIdx.x & 63;
    int i = blockIdx.x * 4 + wave;
    if (i >= n) return;
    int s = start[i], d = deg[i];
    int end = s + d;
    int g = lane >> 3;          // edge slot within 8-batch
    int l = lane & 7;           // head owned in phase 1
    // Q fragment for (node i, head l): channels 16l..16l+15
    const uint4* qh = (const uint4*)(Q + (size_t)i * 128 + l * 16);
    uint4 q0 = qh[0], q1 = qh[1];
    const float SC = 0.25f * 1.44269504089f;   // /sqrt(16) * log2(e)
    float ax = 0.f, ay = 0.f;
    for (int j = s; j < end; j += 8) {
        int eg = j + g;
        int se = esrc[eg < end ? eg : end - 1];
        // phase 1: dot for (edge j+g, head l)
        const uint4* kh = (const uint4*)(K + (size_t)se * 128 + l * 16);
        uint4 k0 = kh[0], k1 = kh[1];
        float p = (dot8f(q0, k0) + dot8f(q1, k1)) * SC;
        float mx = fmaxf(p, __shfl_xor(p, 1));
        mx = fmaxf(mx, __shfl_xor(mx, 2));
        mx = fmaxf(mx, __shfl_xor(mx, 4));
        float ex = exp2f(p - mx);
        float t = ex + __shfl_xor(ex, 1);
        t += __shfl_xor(t, 2);
        t += __shfl_xor(t, 4);
        float wgt = __fdividef(ex, t);
        // phase 2: accumulate up to 8 edges (uniform guard)
        #pragma unroll
        for (int e = 0; e < 8; e++) {
            if (j + e >= end) break;
            float we = __shfl(wgt, e * 8 + (lane >> 3));
            int sv = __shfl(se, e * 8);
            unsigned vu = ((const unsigned*)(V + (size_t)sv * 128))[lane];
            ax += we * blo(vu);
            ay += we * bhi(vu);
        }
    }
    __hip_bfloat162 o2;
    o2.x = __float2bfloat16(ax);
    o2.y = __float2bfloat16(ay);
    ((__hip_bfloat162*)(ag + (size_t)i * 128))[lane] = o2;
}

extern "C" void kernel_launch(void* const* d_in, const int* in_sizes, int n_in,
                              void* d_out, int out_size, void* d_ws, size_t ws_size,
                              hipStream_t stream) {
    const float* x   = (const float*)d_in[0];
    const int*  eidx = (const int*)d_in[1];
    const float* Wq = (const float*)d_in[2];  const float* bq = (const float*)d_in[3];
    const float* Wk = (const float*)d_in[4];  const float* bk = (const float*)d_in[5];
    const float* Wv = (const float*)d_in[6];  const float* bv = (const float*)d_in[7];
    const float* Wo = (const float*)d_in[8];  const float* bo = (const float*)d_in[9];
    const float* W1 = (const float*)d_in[10]; const float* b1 = (const float*)d_in[11];
    const float* W2 = (const float*)d_in[12]; const float* b2 = (const float*)d_in[13];
    const float* g1 = (const float*)d_in[14]; const float* be1 = (const float*)d_in[15];
    const float* g2 = (const float*)d_in[16]; const float* be2 = (const float*)d_in[17];
    float* out = (float*)d_out;

    int n  = in_sizes[0] / C_DIM;   // 100000
    int E_ = in_sizes[1] / 2;       // 600000
    size_t nf = (size_t)n * 128;

    // ---- workspace ----
    bf16* Wt    = (bf16*)d_ws;                // 196608 bf16 transposed weights
    float* bqkv = (float*)(Wt + 196608);      // packed [bq|bk|bv]
    bf16* reg0  = (bf16*)(bqkv + 384);        // 4*nf: h1|Q|K|V ; u overlays all
    bf16* h1 = reg0;
    bf16* Qb = reg0 + nf;
    bf16* Kb = reg0 + 2 * nf;
    bf16* Vb = reg0 + 3 * nf;
    bf16* uB = reg0;                          // [N,512] bf16 (FFN intermediate)
    bf16* ag = reg0 + 4 * nf;                 // [N,128]
    char* r2 = (char*)(ag + nf);              // union region
    int*  esrc   = (int*)r2;                  // [E] CSR-ordered source ids
    int*  ideg   = esrc + E_;
    int*  counter = ideg + n;
    int*  istart  = ideg + n + 1;
    int*  icursor = istart + n;
    bf16* h2 = (bf16*)r2;                     // overlays esrc/CSR after attn_aggr

    dim3 b256(256);
    dim3 lnGrid((n + 3) / 4);
    int rb = (n + 127) / 128;                 // 782
    dim3 eGrid((E_ + 255) / 256);
    dim3 nGrid((n + 255) / 256);
    dim3 n1Grid((n + 1 + 255) / 256);
    dim3 n4Grid((n + 3) / 4);

    // weights -> bf16 transposed + packed bqkv (one dispatch)
    wconv_all<<<dim3(770), b256, 0, stream>>>(Wq, Wk, Wv, Wo, W1, W2, bq, bk, bv, Wt);
    // zero deg+counter
    zeroi_kernel<<<n1Grid, b256, 0, stream>>>(ideg, n + 1);
    // LN1: x -> h1
    ln_kernel<<<lnGrid, b256, 0, stream>>>(x, g1, be1, h1, n);
    // QKV: one dispatch, col-blocks -> Q|K|V buffers (obStride = nf)
    gemm_lds<true, false, false, 1><<<dim3(rb, 3), b256, 0, stream>>>(
        h1, 128, Wt, 128, bqkv, Qb, 128, nf, nullptr, 0, n, nullptr, nullptr, nullptr);
    // CSR build
    hist_kernel<<<eGrid, b256, 0, stream>>>(eidx, ideg, E_);
    alloc_kernel<<<nGrid, b256, 0, stream>>>(ideg, istart, icursor, counter, n);
    scatter_kernel<<<eGrid, b256, 0, stream>>>(eidx, icursor, esrc, E_);
    // fused attention + aggregation into ag
    attn_aggr_kernel<<<n4Grid, b256, 0, stream>>>(Qb, Kb, Vb, istart, ideg, esrc, ag, n);
    // Wo + residual + fused LN2: x2 -> d_out (fp32), h2 (bf16, overlays r2)
    gemm_lds<false, false, true, 1><<<dim3(rb, 1), b256, 0, stream>>>(
        ag, 128, Wt + 49152, 128, bo, out, 128, 0, x, 128, n, g2, be2, h2);
    // FFN1: h2 @ W1 + b1, ReLU -> u [N,512] bf16 (overlays h1|Q|K|V, all dead)
    gemm_lds<true, true, false, 1><<<dim3(rb, 4), b256, 0, stream>>>(
        h2, 128, Wt + 65536, 128, b1, uB, 512, 128, nullptr, 0, n, nullptr, nullptr, nullptr);
    // FFN2: u @ W2 + b2 + x2 -> d_out (K=512 -> 4 k-tiles)
    gemm_lds<false, false, false, 4><<<dim3(rb, 1), b256, 0, stream>>>(
        uB, 512, Wt + 131072, 512, b2, out, 128, 0, out, 128, n, nullptr, nullptr, nullptr);
}

// Round 6
// 456.554 us; speedup vs baseline: 1.1305x; 1.0134x over previous
//
#include <hip/hip_runtime.h>
#include <hip/hip_bf16.h>

#define C_DIM 128
#define EPS_LN 1e-5f

typedef short bf16x8 __attribute__((ext_vector_type(8)));
typedef float f32x4  __attribute__((ext_vector_type(4)));
typedef __hip_bfloat16 bf16;

__device__ inline unsigned short f2bu(float f) {
    bf16 h = __float2bfloat16(f);
    return *reinterpret_cast<unsigned short*>(&h);
}
__device__ inline float blo(unsigned int u) { return __uint_as_float(u << 16); }
__device__ inline float bhi(unsigned int u) { return __uint_as_float(u & 0xffff0000u); }
__device__ inline ushort4 pack4(float a, float b, float c, float d) {
    ushort4 r; r.x = f2bu(a); r.y = f2bu(b); r.z = f2bu(c); r.w = f2bu(d); return r;
}

// async global->LDS DMA, 16B per lane. LDS dest is WAVE-UNIFORM base;
// HW writes lane l's 16B at base + l*16. Global src is per-lane.
__device__ inline void async_copy16(const bf16* g, bf16* s) {
    __builtin_amdgcn_global_load_lds(
        (const __attribute__((address_space(1))) unsigned int*)g,
        (__attribute__((address_space(3))) unsigned int*)s,
        16, 0, 0);
}

// ---------------- weights convert+transpose + bias pack, ONE dispatch ------
// dst (bf16): Wqt|Wkt|Wvt|Wot (4x 128*128) | Wt1[512][128] | Wt2[128][512]
// then packed fp32 bqkv[384] right after.
__global__ __launch_bounds__(256) void wconv_all(
    const float* __restrict__ Wq, const float* __restrict__ Wk,
    const float* __restrict__ Wv, const float* __restrict__ Wo,
    const float* __restrict__ W1, const float* __restrict__ W2,
    const float* __restrict__ bq, const float* __restrict__ bk,
    const float* __restrict__ bv, bf16* __restrict__ dst) {
    int idx = blockIdx.x * 256 + threadIdx.x;
    if (idx < 65536) {                       // four 128x128 weights
        int r = idx >> 14, o = idx & 16383;
        int k = o >> 7, nn = o & 127;
        const float* W = (r == 0) ? Wq : (r == 1) ? Wk : (r == 2) ? Wv : Wo;
        dst[(r << 14) + nn * 128 + k] = __float2bfloat16(W[o]);
    } else if (idx < 131072) {               // W1 [128,512] -> Wt1[n][k]
        int o = idx - 65536;
        int k = o >> 9, nn = o & 511;
        dst[65536 + nn * 128 + k] = __float2bfloat16(W1[o]);
    } else if (idx < 196608) {               // W2 [512,128] -> Wt2[n][k]
        int o = idx - 131072;
        int k = o >> 7, nn = o & 127;
        dst[131072 + nn * 512 + k] = __float2bfloat16(W2[o]);
    } else if (idx < 196992) {               // packed bqkv[384] fp32
        int j = idx - 196608;
        int grp = j >> 7, col = j & 127;
        const float* bp = (grp == 0) ? bq : (grp == 1) ? bk : bv;
        ((float*)(dst + 196608))[j] = bp[col];
    }
}

__global__ __launch_bounds__(256) void zeroi_kernel(int* __restrict__ p, int n) {
    int i = blockIdx.x * 256 + threadIdx.x;
    if (i < n) p[i] = 0;
}

// ---------------- LayerNorm fp32 -> bf16, one wave per row -----------------
__global__ __launch_bounds__(256) void ln_kernel(
    const float* __restrict__ x, const float* __restrict__ g,
    const float* __restrict__ b, bf16* __restrict__ out, int n) {
    int wave = threadIdx.x >> 6;
    int lane = threadIdx.x & 63;
    int row = blockIdx.x * 4 + wave;
    if (row >= n) return;
    float2 v = ((const float2*)(x + (size_t)row * C_DIM))[lane];
    float s  = v.x + v.y;
    float ss = v.x * v.x + v.y * v.y;
    #pragma unroll
    for (int o = 1; o < 64; o <<= 1) {
        s  += __shfl_xor(s, o);
        ss += __shfl_xor(ss, o);
    }
    float mu  = s * (1.0f / C_DIM);
    float var = ss * (1.0f / C_DIM) - mu * mu;
    float rs  = rsqrtf(var + EPS_LN);
    float2 gg = ((const float2*)g)[lane];
    float2 bb = ((const float2*)b)[lane];
    __hip_bfloat162 o2;
    o2.x = __float2bfloat16((v.x - mu) * rs * gg.x + bb.x);
    o2.y = __float2bfloat16((v.y - mu) * rs * gg.y + bb.y);
    ((__hip_bfloat162*)(out + (size_t)row * C_DIM))[lane] = o2;
}

// ---------------- LDS-staged MFMA GEMM (global_load_lds + XOR swizzle) -----
// Block: 128 rows x 128 cols of C; 4 waves, each 32 rows x 128 cols.
// A [M,lda] bf16 row-major; Bt [Ncols][Kfull] bf16 (row = output col).
// Staging: async_copy16, wave-uniform LDS base (linear [128][128]), per-lane
// global src pre-swizzled: LDS slot s of row r holds global slot s^(r&7).
// Reads use ((ks*4+q)^(m&7))<<3 -> bank-uniform (2 lanes/bank, free).
// Tail: clamp source row to M-1 (garbage lands only in C rows >= M, masked).
// NOTE round-3 lesson: A direct-to-reg (64B segments) over-fetches HBM and
// regresses despite 2x occupancy -- keep BOTH operands on the 1KB-contiguous
// DMA path.
// Operand-swapped mfma(bf, af, acc): lane(m,q) reg r = C[row0+..+m][ct*16+q*4+r].
template<bool OUTBF16, bool RELU, bool FUSE_LN, int KSTEPS>
__global__ __launch_bounds__(256) void gemm_lds(
    const bf16* __restrict__ A, int lda,
    const bf16* __restrict__ Bt, int Kfull,
    const float* __restrict__ biasBase,
    void* __restrict__ Cd, int ldc, size_t obStride,
    const float* __restrict__ resid, int ldres,
    int M,
    const float* __restrict__ g, const float* __restrict__ be,
    bf16* __restrict__ h2) {
    __shared__ bf16 As[128][128];
    __shared__ bf16 Bs[128][128];
    int tid  = threadIdx.x;
    int lane = tid & 63;
    int w    = tid >> 6;
    int m = lane & 15, q = lane >> 4;
    int row0 = blockIdx.x * 128;
    const bf16* Bbase = Bt + (size_t)blockIdx.y * 128 * Kfull;

    f32x4 acc[2][8];
    #pragma unroll
    for (int rt = 0; rt < 2; rt++)
        #pragma unroll
        for (int ct = 0; ct < 8; ct++) acc[rt][ct] = (f32x4){0.f, 0.f, 0.f, 0.f};

    int rsub  = lane >> 4;      // 0..3: this lane's dest row within a 4-row DMA call
    int cslot = lane & 15;      // this lane's 16B slot within the row

    for (int kt = 0; kt < KSTEPS; kt++) {
        // stage A+B tiles [128][128] via 8+8 async DMA calls per wave
        #pragma unroll
        for (int i = 0; i < 8; i++) {
            int arow = w * 32 + i * 4 + rsub;                 // dest row 0..127
            int scol = (cslot ^ (arow & 7)) << 3;             // swizzled src slot (elems)
            int garow = row0 + arow;
            if (garow > M - 1) garow = M - 1;                 // tail clamp
            async_copy16(A + (size_t)garow * lda + kt * 128 + scol, &As[w * 32 + i * 4][0]);
            async_copy16(Bbase + (size_t)arow * Kfull + kt * 128 + scol, &Bs[w * 32 + i * 4][0]);
        }
        __syncthreads();
        #pragma unroll
        for (int ks = 0; ks < 4; ks++) {
            int sofs = ((ks * 4 + q) ^ (m & 7)) << 3;         // swizzled read offset
            bf16x8 af0 = *(const bf16x8*)&As[w * 32 + m][sofs];
            bf16x8 af1 = *(const bf16x8*)&As[w * 32 + 16 + m][sofs];
            #pragma unroll
            for (int ct = 0; ct < 8; ct++) {
                bf16x8 bf = *(const bf16x8*)&Bs[ct * 16 + m][sofs];
                acc[0][ct] = __builtin_amdgcn_mfma_f32_16x16x32_bf16(bf, af0, acc[0][ct], 0, 0, 0);
                acc[1][ct] = __builtin_amdgcn_mfma_f32_16x16x32_bf16(bf, af1, acc[1][ct], 0, 0, 0);
            }
        }
        if (kt + 1 < KSTEPS) __syncthreads();
    }

    // ---- epilogue ----
    #pragma unroll
    for (int rt = 0; rt < 2; rt++) {
        int row = row0 + w * 32 + rt * 16 + m;
        bool valid = row < M;
        float vals[8][4];
        #pragma unroll
        for (int ct = 0; ct < 8; ct++) {
            int col = ct * 16 + q * 4;
            float4 bv = make_float4(0.f, 0.f, 0.f, 0.f);
            if (biasBase) bv = *(const float4*)(biasBase + blockIdx.y * 128 + col);
            float4 rv = make_float4(0.f, 0.f, 0.f, 0.f);
            if (resid && valid) rv = *(const float4*)(resid + (size_t)row * ldres + col);
            vals[ct][0] = acc[rt][ct][0] + bv.x + rv.x;
            vals[ct][1] = acc[rt][ct][1] + bv.y + rv.y;
            vals[ct][2] = acc[rt][ct][2] + bv.z + rv.z;
            vals[ct][3] = acc[rt][ct][3] + bv.w + rv.w;
        }
        if (FUSE_LN) {
            // row spans lanes {m, m+16, m+32, m+48}: reduce over q via xor 16,32
            float s1 = 0.f, s2 = 0.f;
            #pragma unroll
            for (int ct = 0; ct < 8; ct++)
                #pragma unroll
                for (int r = 0; r < 4; r++) { s1 += vals[ct][r]; s2 += vals[ct][r] * vals[ct][r]; }
            s1 += __shfl_xor(s1, 16); s1 += __shfl_xor(s1, 32);
            s2 += __shfl_xor(s2, 16); s2 += __shfl_xor(s2, 32);
            float mu  = s1 * (1.0f / 128.f);
            float var = s2 * (1.0f / 128.f) - mu * mu;
            float rs  = rsqrtf(var + EPS_LN);
            if (valid) {
                #pragma unroll
                for (int ct = 0; ct < 8; ct++) {
                    int col = ct * 16 + q * 4;
                    *(float4*)((float*)Cd + (size_t)row * ldc + col) =
                        make_float4(vals[ct][0], vals[ct][1], vals[ct][2], vals[ct][3]);
                    float4 gg = *(const float4*)(g + col);
                    float4 bb = *(const float4*)(be + col);
                    *(ushort4*)(h2 + (size_t)row * 128 + col) =
                        pack4((vals[ct][0] - mu) * rs * gg.x + bb.x,
                              (vals[ct][1] - mu) * rs * gg.y + bb.y,
                              (vals[ct][2] - mu) * rs * gg.z + bb.z,
                              (vals[ct][3] - mu) * rs * gg.w + bb.w);
                }
            }
        } else if (valid) {
            #pragma unroll
            for (int ct = 0; ct < 8; ct++) {
                int col = ct * 16 + q * 4;
                float v0 = vals[ct][0], v1 = vals[ct][1];
                float v2 = vals[ct][2], v3 = vals[ct][3];
                if (RELU) {
                    v0 = fmaxf(v0, 0.f); v1 = fmaxf(v1, 0.f);
                    v2 = fmaxf(v2, 0.f); v3 = fmaxf(v3, 0.f);
                }
                if (OUTBF16) {
                    *(ushort4*)((bf16*)Cd + blockIdx.y * obStride + (size_t)row * ldc + col) =
                        pack4(v0, v1, v2, v3);
                } else {
                    *(float4*)((float*)Cd + blockIdx.y * obStride + (size_t)row * ldc + col) =
                        make_float4(v0, v1, v2, v3);
                }
            }
        }
    }
}

// ---------------- CSR build ------------------------------------------------
__global__ __launch_bounds__(256) void hist_kernel(
    const int* __restrict__ eidx, int* __restrict__ deg, int E_) {
    int e = blockIdx.x * 256 + threadIdx.x;
    if (e >= E_) return;
    atomicAdd(&deg[eidx[E_ + e]], 1);
}

__global__ __launch_bounds__(256) void alloc_kernel(
    const int* __restrict__ deg, int* __restrict__ start,
    int* __restrict__ cursor, int* __restrict__ counter, int n) {
    int i = blockIdx.x * 256 + threadIdx.x;
    if (i >= n) return;
    int d = deg[i];
    int s = atomicAdd(counter, d);
    start[i] = s;
    cursor[i] = s;
}

__global__ __launch_bounds__(256) void scatter_kernel(
    const int* __restrict__ eidx, int* __restrict__ cursor,
    int* __restrict__ esrc, int E_) {
    int e = blockIdx.x * 256 + threadIdx.x;
    if (e >= E_) return;
    int src = eidx[e];
    int dst = eidx[E_ + e];
    int pos = atomicAdd(&cursor[dst], 1);
    esrc[pos] = src;
}

// ---------- fused attention + aggregation: one wave per node ---------------
// Round-6 restructure for memory-level parallelism: the V gathers do NOT
// depend on the softmax, only on esrc. Issue K loads AND all 8 V loads as
// soon as `se` arrives -> ONE exposed gather round per 8-edge batch (was
// two: K...softmax...V). Phase 2 is fully predicated (no break): invalid
// slots clamp to edge end-1 (a row already being loaded -> zero extra
// distinct rows) and get weight 0, so all 8 V loads sit in the VMEM queue
// together instead of issuing behind serialized branches.
// Layout: 8 groups x 8 lanes; group g = edge j+g, lane l in group = head l
// (channels 16l..16l+15). Softmax across heads = xor 1,2,4 within group.
// exp2f with folded 0.25*log2e scale (monotonic -> same argmax); fast div.
// Phase 2: lane holds channels 2*lane,2*lane+1 (head = lane>>3 = g).
__device__ inline float dot8f(uint4 a, uint4 b) {
    return blo(a.x) * blo(b.x) + bhi(a.x) * bhi(b.x)
         + blo(a.y) * blo(b.y) + bhi(a.y) * bhi(b.y)
         + blo(a.z) * blo(b.z) + bhi(a.z) * bhi(b.z)
         + blo(a.w) * blo(b.w) + bhi(a.w) * bhi(b.w);
}

__global__ __launch_bounds__(256) void attn_aggr_kernel(
    const bf16* __restrict__ Q, const bf16* __restrict__ K,
    const bf16* __restrict__ V,
    const int* __restrict__ start, const int* __restrict__ deg,
    const int* __restrict__ esrc, bf16* __restrict__ ag, int n) {
    int wave = threadIdx.x >> 6;
    int lane = threadIdx.x & 63;
    int i = blockIdx.x * 4 + wave;
    if (i >= n) return;
    int s = start[i], d = deg[i];
    int end = s + d;
    int g = lane >> 3;          // edge slot within 8-batch (== head in phase 2)
    int l = lane & 7;           // head owned in phase 1
    // Q fragment for (node i, head l): channels 16l..16l+15
    const uint4* qh = (const uint4*)(Q + (size_t)i * 128 + l * 16);
    uint4 q0 = qh[0], q1 = qh[1];
    const float SC = 0.25f * 1.44269504089f;   // /sqrt(16) * log2(e)
    float ax = 0.f, ay = 0.f;
    for (int j = s; j < end; j += 8) {
        int eg = j + g;
        int se = esrc[eg < end ? eg : end - 1];
        // issue K load (edge j+g, head l) -- does not wait
        const uint4* kh = (const uint4*)(K + (size_t)se * 128 + l * 16);
        uint4 k0 = kh[0], k1 = kh[1];
        // issue ALL 8 V loads now (independent of softmax; only need se)
        unsigned vu[8];
        #pragma unroll
        for (int e = 0; e < 8; e++) {
            int sv = __shfl(se, e * 8);
            vu[e] = ((const unsigned*)(V + (size_t)sv * 128))[lane];
        }
        // softmax over heads (waits on K only; V still in flight)
        float p = (dot8f(q0, k0) + dot8f(q1, k1)) * SC;
        float mx = fmaxf(p, __shfl_xor(p, 1));
        mx = fmaxf(mx, __shfl_xor(mx, 2));
        mx = fmaxf(mx, __shfl_xor(mx, 4));
        float ex = exp2f(p - mx);
        float t = ex + __shfl_xor(ex, 1);
        t += __shfl_xor(t, 2);
        t += __shfl_xor(t, 4);
        float wgt = __fdividef(ex, t);
        // predicated accumulate (no break): invalid edges get weight 0
        #pragma unroll
        for (int e = 0; e < 8; e++) {
            float we = (j + e < end) ? __shfl(wgt, e * 8 + g) : 0.f;
            ax += we * blo(vu[e]);
            ay += we * bhi(vu[e]);
        }
    }
    __hip_bfloat162 o2;
    o2.x = __float2bfloat16(ax);
    o2.y = __float2bfloat16(ay);
    ((__hip_bfloat162*)(ag + (size_t)i * 128))[lane] = o2;
}

extern "C" void kernel_launch(void* const* d_in, const int* in_sizes, int n_in,
                              void* d_out, int out_size, void* d_ws, size_t ws_size,
                              hipStream_t stream) {
    const float* x   = (const float*)d_in[0];
    const int*  eidx = (const int*)d_in[1];
    const float* Wq = (const float*)d_in[2];  const float* bq = (const float*)d_in[3];
    const float* Wk = (const float*)d_in[4];  const float* bk = (const float*)d_in[5];
    const float* Wv = (const float*)d_in[6];  const float* bv = (const float*)d_in[7];
    const float* Wo = (const float*)d_in[8];  const float* bo = (const float*)d_in[9];
    const float* W1 = (const float*)d_in[10]; const float* b1 = (const float*)d_in[11];
    const float* W2 = (const float*)d_in[12]; const float* b2 = (const float*)d_in[13];
    const float* g1 = (const float*)d_in[14]; const float* be1 = (const float*)d_in[15];
    const float* g2 = (const float*)d_in[16]; const float* be2 = (const float*)d_in[17];
    float* out = (float*)d_out;

    int n  = in_sizes[0] / C_DIM;   // 100000
    int E_ = in_sizes[1] / 2;       // 600000
    size_t nf = (size_t)n * 128;

    // ---- workspace ----
    bf16* Wt    = (bf16*)d_ws;                // 196608 bf16 transposed weights
    float* bqkv = (float*)(Wt + 196608);      // packed [bq|bk|bv]
    bf16* reg0  = (bf16*)(bqkv + 384);        // 4*nf: h1|Q|K|V ; u overlays all
    bf16* h1 = reg0;
    bf16* Qb = reg0 + nf;
    bf16* Kb = reg0 + 2 * nf;
    bf16* Vb = reg0 + 3 * nf;
    bf16* uB = reg0;                          // [N,512] bf16 (FFN intermediate)
    bf16* ag = reg0 + 4 * nf;                 // [N,128]
    char* r2 = (char*)(ag + nf);              // union region
    int*  esrc   = (int*)r2;                  // [E] CSR-ordered source ids
    int*  ideg   = esrc + E_;
    int*  counter = ideg + n;
    int*  istart  = ideg + n + 1;
    int*  icursor = istart + n;
    bf16* h2 = (bf16*)r2;                     // overlays esrc/CSR after attn_aggr

    dim3 b256(256);
    dim3 lnGrid((n + 3) / 4);
    int rb = (n + 127) / 128;                 // 782
    dim3 eGrid((E_ + 255) / 256);
    dim3 nGrid((n + 255) / 256);
    dim3 n1Grid((n + 1 + 255) / 256);
    dim3 n4Grid((n + 3) / 4);

    // weights -> bf16 transposed + packed bqkv (one dispatch)
    wconv_all<<<dim3(770), b256, 0, stream>>>(Wq, Wk, Wv, Wo, W1, W2, bq, bk, bv, Wt);
    // zero deg+counter
    zeroi_kernel<<<n1Grid, b256, 0, stream>>>(ideg, n + 1);
    // LN1: x -> h1
    ln_kernel<<<lnGrid, b256, 0, stream>>>(x, g1, be1, h1, n);
    // QKV: one dispatch, col-blocks -> Q|K|V buffers (obStride = nf)
    gemm_lds<true, false, false, 1><<<dim3(rb, 3), b256, 0, stream>>>(
        h1, 128, Wt, 128, bqkv, Qb, 128, nf, nullptr, 0, n, nullptr, nullptr, nullptr);
    // CSR build
    hist_kernel<<<eGrid, b256, 0, stream>>>(eidx, ideg, E_);
    alloc_kernel<<<nGrid, b256, 0, stream>>>(ideg, istart, icursor, counter, n);
    scatter_kernel<<<eGrid, b256, 0, stream>>>(eidx, icursor, esrc, E_);
    // fused attention + aggregation into ag
    attn_aggr_kernel<<<n4Grid, b256, 0, stream>>>(Qb, Kb, Vb, istart, ideg, esrc, ag, n);
    // Wo + residual + fused LN2: x2 -> d_out (fp32), h2 (bf16, overlays r2)
    gemm_lds<false, false, true, 1><<<dim3(rb, 1), b256, 0, stream>>>(
        ag, 128, Wt + 49152, 128, bo, out, 128, 0, x, 128, n, g2, be2, h2);
    // FFN1: h2 @ W1 + b1, ReLU -> u [N,512] bf16 (overlays h1|Q|K|V, all dead)
    gemm_lds<true, true, false, 1><<<dim3(rb, 4), b256, 0, stream>>>(
        h2, 128, Wt + 65536, 128, b1, uB, 512, 128, nullptr, 0, n, nullptr, nullptr, nullptr);
    // FFN2: u @ W2 + b2 + x2 -> d_out (K=512 -> 4 k-tiles)
    gemm_lds<false, false, false, 4><<<dim3(rb, 1), b256, 0, stream>>>(
        uB, 512, Wt + 131072, 512, b2, out, 128, 0, out, 128, n, nullptr, nullptr, nullptr);
}